// Round 10
// baseline (147.883 us; speedup 1.0000x reference)
//
#include <hip/hip_runtime.h>
#include <math.h>

#define KNN 5
#define BLOCK 256

// ---- cell grid ----
#define G 28
#define NC (G * G * G)        // 21952
#define NCPAD 24576           // padded for scan kernel (1024*24)
#define GRANGE 6.0f
#define H (2.0f * GRANGE / (float)G)
#define INVH ((float)G / (2.0f * GRANGE))
#define LPS 16                // lanes per source (query kernel)
#define SPC (BLOCK / LPS)     // sources per chunk (16)
#define QBLOCKS 512           // query grid
#define TBLOCKS 128           // tail-walker grid (128*4 = 512 waves)

// ---- fallback (round-4 split path) params ----
#define TILE_T 2048
#define WAVES_PER_BLOCK (BLOCK / 64)
#define SRCW 8
#define SRC_PER_BLOCK (WAVES_PER_BLOCK * SRCW)
#define NSPLIT 2

__device__ __forceinline__ float vmin(float a, float b) {
    float r;
    asm("v_min_f32 %0, %1, %2" : "=v"(r) : "v"(a), "v"(b));
    return r;
}
__device__ __forceinline__ float vmax(float a, float b) {
    float r;
    asm("v_max_f32 %0, %1, %2" : "=v"(r) : "v"(a), "v"(b));
    return r;
}

// sorted top-5 insert: min(Kb,max(Ka,v)) == med3(Ka,Kb,v) for Ka<=Kb
#define INS5(K0, K1, K2, K3, K4, V)                                       \
    do {                                                                  \
        float _v = (V);                                                   \
        K4 = __builtin_amdgcn_fmed3f(K3, K4, _v);                         \
        K3 = __builtin_amdgcn_fmed3f(K2, K3, _v);                         \
        K2 = __builtin_amdgcn_fmed3f(K1, K2, _v);                         \
        K1 = __builtin_amdgcn_fmed3f(K0, K1, _v);                         \
        K0 = vmin(K0, _v);                                                \
    } while (0)

// lowest-5 of two sorted-5 lists (result in a0..a4)
#define MERGE55(a0, a1, a2, a3, a4, b0, b1, b2, b3, b4)                   \
    do {                                                                  \
        float r0 = vmin(a0, b0);                                          \
        float r1 = vmin(vmin(a1, b1), vmax(a0, b0));                      \
        float r2 = vmin(vmin(a2, b2), vmin(vmax(a0, b1), vmax(a1, b0)));  \
        float r3 = vmin(vmin(a3, b3),                                     \
                        vmin(vmax(a0, b2), vmin(vmax(a1, b1), vmax(a2, b0)))); \
        float r4 = vmin(vmin(a4, b4),                                     \
                        vmin(vmin(vmax(a0, b3), vmax(a1, b2)),            \
                             vmin(vmax(a2, b1), vmax(a3, b0))));          \
        a0 = r0; a1 = r1; a2 = r2; a3 = r3; a4 = r4;                      \
    } while (0)

// ---------------- tiny kernels (fallback path) ----------------
__global__ void finalize_kernel(const float* acc, float* out) {
    out[0] = acc[0] / (acc[1] * (float)KNN);
}
__global__ void init_acc_kernel(float* acc) { acc[0] = 0.0f; acc[1] = 0.0f; }

// ================= grid pipeline =================

__device__ __forceinline__ int cell_of(float x, float y, float z) {
    int cx = (int)floorf((x + GRANGE) * INVH);
    int cy = (int)floorf((y + GRANGE) * INVH);
    int cz = (int)floorf((z + GRANGE) * INVH);
    cx = min(max(cx, 0), G - 1);
    cy = min(max(cy, 0), G - 1);
    cz = min(max(cz, 0), G - 1);
    return (cz * G + cy) * G + cx;
}

__global__ void bin_count_kernel(const float* __restrict__ src,
                                 const float* __restrict__ tgt,
                                 int ms, int nt,
                                 int* __restrict__ cnt_s,
                                 int* __restrict__ cnt_t) {
    int i = blockIdx.x * blockDim.x + threadIdx.x;
    int n = ms + nt;
    for (; i < n; i += gridDim.x * blockDim.x) {
        bool isT = (i >= ms);
        const float* p = isT ? (tgt + 3 * (size_t)(i - ms)) : (src + 3 * (size_t)i);
        float x = p[0], y = p[1], z = p[2];
        if (isT && x == 0.0f && y == 0.0f && z == 0.0f) continue;
        atomicAdd((isT ? cnt_t : cnt_s) + cell_of(x, y, z), 1);
    }
}

// exclusive scan of NCPAD padded counts; block 0 -> targets, 1 -> sources.
__global__ __launch_bounds__(1024) void scan_kernel(int* ct, int* ot, int* cs, int* os) {
    __shared__ int psum[1024];
    int* c = blockIdx.x ? cs : ct;
    int* o = blockIdx.x ? os : ot;
    const int t = threadIdx.x;
    int4 v[6];
    const int4* c4 = reinterpret_cast<const int4*>(c) + t * 6;
#pragma unroll
    for (int j = 0; j < 6; ++j) v[j] = c4[j];
    int s = 0;
#pragma unroll
    for (int j = 0; j < 6; ++j) s += v[j].x + v[j].y + v[j].z + v[j].w;
    psum[t] = s;
    __syncthreads();
    for (int d = 1; d < 1024; d <<= 1) {
        int x = (t >= d) ? psum[t - d] : 0;
        __syncthreads();
        psum[t] += x;
        __syncthreads();
    }
    int run = t ? psum[t - 1] : 0;
    int4* o4 = reinterpret_cast<int4*>(o) + t * 6;
    int4* cc4 = reinterpret_cast<int4*>(c) + t * 6;
#pragma unroll
    for (int j = 0; j < 6; ++j) {
        int4 w;
        w.x = run; run += v[j].x;
        w.y = run; run += v[j].y;
        w.z = run; run += v[j].z;
        w.w = run; run += v[j].w;
        o4[j] = w;
        cc4[j] = w;  // cursor for scatter
    }
    if (t == 1023) o[NCPAD] = run;
}

__global__ void scatter_kernel(const float* __restrict__ src,
                               const float* __restrict__ tgt,
                               int ms, int nt,
                               int* __restrict__ cur_s, int* __restrict__ cur_t,
                               float4* __restrict__ pts_s,
                               float4* __restrict__ pts_t) {
    int i = blockIdx.x * blockDim.x + threadIdx.x;
    int n = ms + nt;
    for (; i < n; i += gridDim.x * blockDim.x) {
        bool isT = (i >= ms);
        const float* p = isT ? (tgt + 3 * (size_t)(i - ms)) : (src + 3 * (size_t)i);
        float x = p[0], y = p[1], z = p[2];
        if (isT && x == 0.0f && y == 0.0f && z == 0.0f) continue;
        int cell = cell_of(x, y, z);
        int slot = atomicAdd((isT ? cur_t : cur_s) + cell, 1);
        float w = fmaf(x, x, fmaf(y, y, z * z));
        (isT ? pts_t : pts_s)[slot] = make_float4(x, y, z, w);
    }
}

// ---- query: chunks of 16 consecutive sources, 16 lanes each; blocks
// grid-stride over chunks. Ring<=1 prefetched+slab-pruned; sources whose
// exact d5 exceeds H go to the tail worklist. ----
__global__ __launch_bounds__(BLOCK) void knn_query_kernel(
        const float4* __restrict__ pts_s, const float4* __restrict__ pts_t,
        const int* __restrict__ off_t, float* __restrict__ acc,
        int* __restrict__ tail, int* __restrict__ tailcnt, int ms, int nchunk) {
    __shared__ float redS[4], redC[4];

    const int tid = threadIdx.x;
    const int g = tid >> 4;
    const int m = tid & 15;
    float tsum = 0.0f, tcnt = 0.0f;

    for (int c = blockIdx.x; c < nchunk; c += gridDim.x) {
        const int sidx = c * SPC + g;
        const bool live = (sidx < ms);

        float4 sp = pts_s[live ? sidx : 0];
        const float s2 = sp.w;
        const float nx = -2.0f * sp.x, ny = -2.0f * sp.y, nz = -2.0f * sp.z;

        int cx = (int)floorf((sp.x + GRANGE) * INVH);
        int cy = (int)floorf((sp.y + GRANGE) * INVH);
        int cz = (int)floorf((sp.z + GRANGE) * INVH);
        cx = min(max(cx, 0), G - 1);
        cy = min(max(cy, 0), G - 1);
        cz = min(max(cz, 0), G - 1);
        const int xlo = max(cx - 1, 0), xhi = min(cx + 1, G - 1);
        const float y0 = -GRANGE + cy * H, y1 = y0 + H;
        const float z0 = -GRANGE + cz * H, z1 = z0 + H;

        // ---- prefetch all 9 row ranges (independent loads, one batch) ----
        const int DY[9] = {0, -1, 1, 0, 0, -1, -1, 1, 1};
        const int DZ[9] = {0, 0, 0, -1, 1, -1, 1, -1, 1};
        int rst[9], ren[9];
        float rb[9];
#pragma unroll
        for (int r = 0; r < 9; ++r) {
            const int yy = cy + DY[r], zz = cz + DZ[r];
            const bool ok = ((unsigned)yy < G) && ((unsigned)zz < G);
            const int base = (zz * G + yy) * G;
            rst[r] = ok ? off_t[base + xlo] : 0;
            ren[r] = ok ? off_t[base + xhi + 1] : 0;
            float dys = (DY[r] < 0) ? (sp.y - y0) : ((DY[r] > 0) ? (y1 - sp.y) : 0.0f);
            float dzs = (DZ[r] < 0) ? (sp.z - z0) : ((DZ[r] > 0) ? (z1 - sp.z) : 0.0f);
            dys = fmaxf(dys, 0.0f);  // clamped sources sit outside their cell
            dzs = fmaxf(dzs, 0.0f);
            rb[r] = fmaf(dys, dys, dzs * dzs);
        }

        // two interleaved top-5 chains (q = d^2 - s2)
        float a0 = 1e20f, a1 = 1e20f, a2 = 1e20f, a3 = 1e20f, a4 = 1e20f;
        float b0 = 1e20f, b1 = 1e20f, b2 = 1e20f, b3 = 1e20f, b4 = 1e20f;

        auto scan_range = [&](int st, int en) {
            for (int i = st + m; i < en; i += 2 * LPS) {
                float4 t1 = pts_t[i];
                int i2 = i + LPS;
                bool h2 = (i2 < en);
                float4 t2 = pts_t[h2 ? i2 : i];
                float qa = fmaf(nx, t1.x, fmaf(ny, t1.y, fmaf(nz, t1.z, t1.w)));
                float qb = h2 ? fmaf(nx, t2.x, fmaf(ny, t2.y, fmaf(nz, t2.z, t2.w)))
                              : 1e20f;
                INS5(a0, a1, a2, a3, a4, qa);
                INS5(b0, b1, b2, b3, b4, qb);
            }
        };

        // own row first (unpruned)
        scan_range(rst[0], ren[0]);

        // merged d5^2 after own row (non-destructive group merge)
        float lim;
        {
            float m0 = a0, m1 = a1, m2 = a2, m3 = a3, m4 = a4;
            MERGE55(m0, m1, m2, m3, m4, b0, b1, b2, b3, b4);
#pragma unroll
            for (int o = 8; o >= 1; o >>= 1) {
                float c0 = __shfl_xor(m0, o);
                float c1 = __shfl_xor(m1, o);
                float c2 = __shfl_xor(m2, o);
                float c3 = __shfl_xor(m3, o);
                float c4 = __shfl_xor(m4, o);
                MERGE55(m0, m1, m2, m3, m4, c0, c1, c2, c3, c4);
            }
            lim = m4 + s2;
        }

        // remaining 8 rows, slab-pruned (prune is conservative-exact)
#pragma unroll
        for (int r = 1; r < 9; ++r) {
            if (lim > rb[r]) scan_range(rst[r], ren[r]);
        }

        // final merge (destructive; all lanes end with the result)
        MERGE55(a0, a1, a2, a3, a4, b0, b1, b2, b3, b4);
#pragma unroll
        for (int o = 8; o >= 1; o >>= 1) {
            float c0 = __shfl_xor(a0, o);
            float c1 = __shfl_xor(a1, o);
            float c2 = __shfl_xor(a2, o);
            float c3 = __shfl_xor(a3, o);
            float c4 = __shfl_xor(a4, o);
            MERGE55(a0, a1, a2, a3, a4, c0, c1, c2, c3, c4);
        }

        if (live && m == 0) {
            const bool valid = (sp.x != 0.0f) || (sp.y != 0.0f) || (sp.z != 0.0f);
            if (valid) {
                const bool inbox = fabsf(sp.x) <= GRANGE &&
                                   fabsf(sp.y) <= GRANGE && fabsf(sp.z) <= GRANGE;
                if (inbox && (a4 + s2 <= H * H)) {  // unscanned space >= H away
                    tsum += sqrtf(fmaxf(a0 + s2, 1e-12f)) +
                            sqrtf(fmaxf(a1 + s2, 1e-12f)) +
                            sqrtf(fmaxf(a2 + s2, 1e-12f)) +
                            sqrtf(fmaxf(a3 + s2, 1e-12f)) +
                            sqrtf(fmaxf(a4 + s2, 1e-12f));
                    tcnt += 1.0f;
                } else {
                    int ti = atomicAdd(tailcnt, 1);
                    tail[ti] = sidx;
                }
            }
        }
    }

    // block reduce -> 2 atomics
#pragma unroll
    for (int off = 32; off >= 1; off >>= 1) {
        tsum += __shfl_down(tsum, off);
        tcnt += __shfl_down(tcnt, off);
    }
    const int wv = tid >> 6;
    if ((tid & 63) == 0) { redS[wv] = tsum; redC[wv] = tcnt; }
    __syncthreads();
    if (tid == 0) {
        float s = redS[0] + redS[1] + redS[2] + redS[3];
        float c = redC[0] + redC[1] + redC[2] + redC[3];
        if (s != 0.0f || c != 0.0f) {
            atomicAdd(&acc[0], s);
            atomicAdd(&acc[1], c);
        }
    }
}

// ---- tail walker: ONE WAVE per tail source, expanding Chebyshev shells,
// exact stop (merged d5^2 <= (r*H)^2, or whole grid covered). Finalizes. ----
__global__ __launch_bounds__(BLOCK) void knnT_kernel(
        const float4* __restrict__ pts_s, const float4* __restrict__ pts_t,
        const int* __restrict__ off_t, const int* __restrict__ tail,
        const int* __restrict__ tailcnt, float* __restrict__ acc,
        int* __restrict__ ticket, float* __restrict__ out) {
    __shared__ float redS[4], redC[4];
    const int T = *tailcnt;
    const int tid = threadIdx.x;
    const int lane = tid & 63, wv = tid >> 6;
    const int wid = blockIdx.x * WAVES_PER_BLOCK + wv;
    const int nwaves = gridDim.x * WAVES_PER_BLOCK;

    float wsum = 0.0f, wcnt = 0.0f;  // meaningful on lane 0

    for (int w = wid; w < T; w += nwaves) {
        const int sidx = tail[w];
        float4 sp = pts_s[sidx];  // wave-uniform
        const float s2 = sp.w;
        const float nx = -2.0f * sp.x, ny = -2.0f * sp.y, nz = -2.0f * sp.z;

        int cx = (int)floorf((sp.x + GRANGE) * INVH);
        int cy = (int)floorf((sp.y + GRANGE) * INVH);
        int cz = (int)floorf((sp.z + GRANGE) * INVH);
        cx = min(max(cx, 0), G - 1);
        cy = min(max(cy, 0), G - 1);
        cz = min(max(cz, 0), G - 1);
        const bool inbox = fabsf(sp.x) <= GRANGE && fabsf(sp.y) <= GRANGE &&
                           fabsf(sp.z) <= GRANGE;
        const int covermax = max(max(max(cx, G - 1 - cx), max(cy, G - 1 - cy)),
                                 max(cz, G - 1 - cz));

        float a0 = 1e20f, a1 = 1e20f, a2 = 1e20f, a3 = 1e20f, a4 = 1e20f;

        auto scan_cells = [&](int yy, int zz, int xa, int xb) {
            if ((unsigned)yy >= G || (unsigned)zz >= G) return;
            xa = max(xa, 0);
            xb = min(xb, G - 1);
            if (xa > xb) return;
            const int base = (zz * G + yy) * G;
            const int st = off_t[base + xa];
            const int en = off_t[base + xb + 1];
            for (int i = st + lane; i < en; i += 64) {
                float4 t = pts_t[i];
                float q = fmaf(nx, t.x, fmaf(ny, t.y, fmaf(nz, t.z, t.w)));
                INS5(a0, a1, a2, a3, a4, q);
            }
        };

        for (int r = 0; r < G; ++r) {
            if (r == 0) {
                scan_cells(cy, cz, cx, cx);
            } else {
                for (int dz = -r; dz <= r; ++dz) {
                    const int zz = cz + dz;
                    const bool zperim = (dz == -r || dz == r);
                    for (int dy = -r; dy <= r; ++dy) {
                        const int yy = cy + dy;
                        if (zperim || dy == -r || dy == r) {
                            scan_cells(yy, zz, cx - r, cx + r);
                        } else {
                            scan_cells(yy, zz, cx - r, cx - r);
                            scan_cells(yy, zz, cx + r, cx + r);
                        }
                    }
                }
            }
            // non-destructive 64-lane merge for the stop check
            float m0 = a0, m1 = a1, m2 = a2, m3 = a3, m4 = a4;
#pragma unroll
            for (int o = 32; o >= 1; o >>= 1) {
                float c0 = __shfl_xor(m0, o);
                float c1 = __shfl_xor(m1, o);
                float c2 = __shfl_xor(m2, o);
                float c3 = __shfl_xor(m3, o);
                float c4 = __shfl_xor(m4, o);
                MERGE55(m0, m1, m2, m3, m4, c0, c1, c2, c3, c4);
            }
            const float rh = (float)r * H;
            if ((inbox && (m4 + s2 <= rh * rh)) || r >= covermax) break;
        }

        // final destructive merge
#pragma unroll
        for (int o = 32; o >= 1; o >>= 1) {
            float c0 = __shfl_xor(a0, o);
            float c1 = __shfl_xor(a1, o);
            float c2 = __shfl_xor(a2, o);
            float c3 = __shfl_xor(a3, o);
            float c4 = __shfl_xor(a4, o);
            MERGE55(a0, a1, a2, a3, a4, c0, c1, c2, c3, c4);
        }

        if (lane == 0) {
            wsum += sqrtf(fmaxf(a0 + s2, 1e-12f)) + sqrtf(fmaxf(a1 + s2, 1e-12f)) +
                    sqrtf(fmaxf(a2 + s2, 1e-12f)) + sqrtf(fmaxf(a3 + s2, 1e-12f)) +
                    sqrtf(fmaxf(a4 + s2, 1e-12f));
            wcnt += 1.0f;
        }
    }

    if (lane == 0) { redS[wv] = wsum; redC[wv] = wcnt; }
    __syncthreads();
    if (tid == 0) {
        float s = redS[0] + redS[1] + redS[2] + redS[3];
        float c = redC[0] + redC[1] + redC[2] + redC[3];
        if (s != 0.0f || c != 0.0f) {
            atomicAdd(&acc[0], s);
            atomicAdd(&acc[1], c);
        }
        __threadfence();
        int t = atomicAdd(ticket, 1);
        if (t == (int)gridDim.x - 1) {
            float ss = atomicAdd(&acc[0], 0.0f);  // coherent read
            float cc = atomicAdd(&acc[1], 0.0f);
            out[0] = ss / (cc * (float)KNN);
        }
    }
}

// ================= fallback: round-4 split path =================

__global__ __launch_bounds__(BLOCK, 4) void knn_split_kernel(
        const float* __restrict__ src, const float* __restrict__ tgt,
        float* __restrict__ partials, int ms, int nt, int nth, int spad) {
    __shared__ __align__(16) float xs[TILE_T];
    __shared__ __align__(16) float ys[TILE_T];
    __shared__ __align__(16) float zs[TILE_T];
    __shared__ __align__(16) float w2[TILE_T];

    const int tid = threadIdx.x;
    const int wv = tid >> 6;
    const int lane = tid & 63;
    const int sbase = (blockIdx.x * WAVES_PER_BLOCK + wv) * SRCW;
    const int half = blockIdx.y;
    const int hbase = half * nth;
    const int hend = min(nt, hbase + nth);

    float nx[SRCW], ny[SRCW], nz[SRCW];
#pragma unroll
    for (int s = 0; s < SRCW; ++s) {
        int sp = sbase + s;
        float x = 0.0f, y = 0.0f, z = 0.0f;
        if (sp < ms) {
            x = src[3 * sp + 0];
            y = src[3 * sp + 1];
            z = src[3 * sp + 2];
        }
        nx[s] = -2.0f * x; ny[s] = -2.0f * y; nz[s] = -2.0f * z;
    }
    float q0[SRCW], q1[SRCW], q2[SRCW], q3[SRCW], q4[SRCW];
#pragma unroll
    for (int s = 0; s < SRCW; ++s) {
        q0[s] = 1e30f; q1[s] = 1e30f; q2[s] = 1e30f; q3[s] = 1e30f; q4[s] = 1e30f;
    }

    for (int t0 = hbase; t0 < hend; t0 += TILE_T) {
        int cnt = min(TILE_T, hend - t0);
        for (int t = tid; t < TILE_T; t += BLOCK) {
            float x = 1e10f, y = 0.0f, z = 0.0f;
            if (t < cnt) {
                x = tgt[3 * (size_t)(t0 + t) + 0];
                y = tgt[3 * (size_t)(t0 + t) + 1];
                z = tgt[3 * (size_t)(t0 + t) + 2];
                if (x == 0.0f && y == 0.0f && z == 0.0f) { x = 1e10f; y = 0.0f; z = 0.0f; }
            }
            xs[t] = x; ys[t] = y; zs[t] = z;
            w2[t] = fmaf(x, x, fmaf(y, y, z * z));
        }
        __syncthreads();
#pragma unroll 2
        for (int i = 0; i < TILE_T / 256; ++i) {
            int t = (i << 8) + (lane << 2);
            float4 x4 = *reinterpret_cast<const float4*>(&xs[t]);
            float4 y4 = *reinterpret_cast<const float4*>(&ys[t]);
            float4 z4 = *reinterpret_cast<const float4*>(&zs[t]);
            float4 w4 = *reinterpret_cast<const float4*>(&w2[t]);
#pragma unroll
            for (int s = 0; s < SRCW; ++s) {
                float qa = fmaf(nx[s], x4.x, fmaf(ny[s], y4.x, fmaf(nz[s], z4.x, w4.x)));
                float qb = fmaf(nx[s], x4.y, fmaf(ny[s], y4.y, fmaf(nz[s], z4.y, w4.y)));
                float qc = fmaf(nx[s], x4.z, fmaf(ny[s], y4.z, fmaf(nz[s], z4.z, w4.z)));
                float qd = fmaf(nx[s], x4.w, fmaf(ny[s], y4.w, fmaf(nz[s], z4.w, w4.w)));
                INS5(q0[s], q1[s], q2[s], q3[s], q4[s], qa);
                INS5(q0[s], q1[s], q2[s], q3[s], q4[s], qb);
                INS5(q0[s], q1[s], q2[s], q3[s], q4[s], qc);
                INS5(q0[s], q1[s], q2[s], q3[s], q4[s], qd);
            }
        }
        __syncthreads();
    }
#pragma unroll
    for (int off = 32; off >= 1; off >>= 1) {
#pragma unroll
        for (int s = 0; s < SRCW; ++s) {
            float b0 = __shfl_xor(q0[s], off);
            float b1 = __shfl_xor(q1[s], off);
            float b2 = __shfl_xor(q2[s], off);
            float b3 = __shfl_xor(q3[s], off);
            float b4 = __shfl_xor(q4[s], off);
            MERGE55(q0[s], q1[s], q2[s], q3[s], q4[s], b0, b1, b2, b3, b4);
        }
    }
    if (lane == 0) {
        float* base = partials + ((size_t)half * spad + sbase) * 8;
#pragma unroll
        for (int s = 0; s < SRCW; ++s) {
            if (sbase + s < ms) {
                *reinterpret_cast<float4*>(base + 8 * s) =
                    make_float4(q0[s], q1[s], q2[s], q3[s]);
                *reinterpret_cast<float4*>(base + 8 * s + 4) =
                    make_float4(q4[s], 0.0f, 0.0f, 0.0f);
            }
        }
    }
}

__global__ __launch_bounds__(BLOCK) void merge_kernel(
        const float* __restrict__ src, const float* __restrict__ partials,
        float* __restrict__ acc, int ms, int spad) {
    __shared__ float red_s[WAVES_PER_BLOCK];
    __shared__ float red_c[WAVES_PER_BLOCK];
    const int tid = threadIdx.x;
    const int sp = blockIdx.x * BLOCK + tid;
    float ssum = 0.0f, scnt = 0.0f;
    if (sp < ms) {
        const float* r0p = partials + (size_t)sp * 8;
        const float* r1p = partials + ((size_t)spad + sp) * 8;
        float4 lo0 = *reinterpret_cast<const float4*>(r0p);
        float a4 = r0p[4];
        float4 lo1 = *reinterpret_cast<const float4*>(r1p);
        float b4 = r1p[4];
        float a0 = lo0.x, a1 = lo0.y, a2 = lo0.z, a3 = lo0.w;
        MERGE55(a0, a1, a2, a3, a4, lo1.x, lo1.y, lo1.z, lo1.w, b4);
        float x = src[3 * sp + 0];
        float y = src[3 * sp + 1];
        float z = src[3 * sp + 2];
        bool valid = (x != 0.0f) || (y != 0.0f) || (z != 0.0f);
        float s2 = fmaf(x, x, fmaf(y, y, z * z));
        if (valid) {
            ssum = sqrtf(fmaxf(a0 + s2, 1e-12f)) + sqrtf(fmaxf(a1 + s2, 1e-12f)) +
                   sqrtf(fmaxf(a2 + s2, 1e-12f)) + sqrtf(fmaxf(a3 + s2, 1e-12f)) +
                   sqrtf(fmaxf(a4 + s2, 1e-12f));
            scnt = 1.0f;
        }
    }
#pragma unroll
    for (int off = 32; off >= 1; off >>= 1) {
        ssum += __shfl_down(ssum, off);
        scnt += __shfl_down(scnt, off);
    }
    if ((tid & 63) == 0) { red_s[tid >> 6] = ssum; red_c[tid >> 6] = scnt; }
    __syncthreads();
    if (tid == 0) {
        float s = 0.0f, c = 0.0f;
#pragma unroll
        for (int i = 0; i < WAVES_PER_BLOCK; ++i) { s += red_s[i]; c += red_c[i]; }
        atomicAdd(&acc[0], s);
        atomicAdd(&acc[1], c);
    }
}

// ---------------- launch ----------------

extern "C" void kernel_launch(void* const* d_in, const int* in_sizes, int n_in,
                              void* d_out, int out_size, void* d_ws, size_t ws_size,
                              hipStream_t stream) {
    const float* src = (const float*)d_in[0];
    const float* tgt = (const float*)d_in[1];
    const int ms = in_sizes[0] / 3;
    const int nt = in_sizes[1] / 3;

    // workspace layout (zeroed header first: acc, ticket, tailcnt, cnt_t/s)
    char* p = (char*)d_ws;
    auto take = [&p](size_t bytes) {
        char* r = p;
        p += (bytes + 15) & ~(size_t)15;
        return r;
    };
    float* acc    = (float*)take(16);            // acc[0], acc[1], ticket, tailcnt
    int* ticket   = (int*)(acc + 2);
    int* tailcnt  = (int*)(acc + 3);
    int* cnt_t    = (int*)take(NCPAD * sizeof(int));
    int* cnt_s    = (int*)take(NCPAD * sizeof(int));
    const size_t zero_bytes = (size_t)((char*)(cnt_s + NCPAD) - (char*)d_ws);
    int* off_t    = (int*)take((NCPAD + 1) * sizeof(int));
    int* off_s    = (int*)take((NCPAD + 1) * sizeof(int));
    float4* pts_t = (float4*)take((size_t)nt * sizeof(float4));
    float4* pts_s = (float4*)take((size_t)ms * sizeof(float4));
    int* tail     = (int*)take((size_t)ms * sizeof(int));
    const size_t need_grid = (size_t)(p - (char*)d_ws);

    if (ws_size >= need_grid) {
        const int n = ms + nt;
        hipMemsetAsync(d_ws, 0, zero_bytes, stream);
        bin_count_kernel<<<(n + 255) / 256, 256, 0, stream>>>(src, tgt, ms, nt,
                                                              cnt_s, cnt_t);
        scan_kernel<<<2, 1024, 0, stream>>>(cnt_t, off_t, cnt_s, off_s);
        scatter_kernel<<<(n + 255) / 256, 256, 0, stream>>>(src, tgt, ms, nt,
                                                            cnt_s, cnt_t, pts_s, pts_t);
        const int nchunk = (ms + SPC - 1) / SPC;
        knn_query_kernel<<<QBLOCKS, BLOCK, 0, stream>>>(pts_s, pts_t, off_t, acc,
                                                        tail, tailcnt, ms, nchunk);
        knnT_kernel<<<TBLOCKS, BLOCK, 0, stream>>>(pts_s, pts_t, off_t, tail,
                                                   tailcnt, acc, ticket,
                                                   (float*)d_out);
        return;
    }

    // fallback: round-4 split path
    float* acc2 = (float*)d_ws;
    init_acc_kernel<<<1, 1, 0, stream>>>(acc2);
    const int ngroups = (ms + SRC_PER_BLOCK - 1) / SRC_PER_BLOCK;
    const int spad = ngroups * SRC_PER_BLOCK;
    int nth = (nt + NSPLIT - 1) / NSPLIT;
    nth = (nth + TILE_T - 1) / TILE_T * TILE_T;
    float* partials = (float*)((char*)d_ws + 16);
    dim3 grid(ngroups, NSPLIT);
    knn_split_kernel<<<grid, BLOCK, 0, stream>>>(src, tgt, partials, ms, nt, nth, spad);
    merge_kernel<<<(ms + BLOCK - 1) / BLOCK, BLOCK, 0, stream>>>(src, partials,
                                                                 acc2, ms, spad);
    finalize_kernel<<<1, 1, 0, stream>>>(acc2, (float*)d_out);
}

// Round 11
// 116.016 us; speedup vs baseline: 1.2747x; 1.2747x over previous
//
#include <hip/hip_runtime.h>
#include <math.h>

#define KNN 5
#define BLOCK 256

// ---- cell grid ----
#define G 28
#define NC (G * G * G)        // 21952
#define NCPAD 24576           // padded for scan kernel (1024*24)
#define GRANGE 6.0f
#define H (2.0f * GRANGE / (float)G)
#define INVH ((float)G / (2.0f * GRANGE))
#define LPS 16                // lanes per source (query kernel)
#define SPC (BLOCK / LPS)     // sources per chunk (16)
#define QBLOCKS 1024          // query grid (1 chunk per block)
#define TBLOCKS 256           // tail-walker grid (256*4 = 1024 waves)

// ---- fallback (round-4 split path) params ----
#define TILE_T 2048
#define WAVES_PER_BLOCK (BLOCK / 64)
#define SRCW 8
#define SRC_PER_BLOCK (WAVES_PER_BLOCK * SRCW)
#define NSPLIT 2

__device__ __forceinline__ float vmin(float a, float b) {
    float r;
    asm("v_min_f32 %0, %1, %2" : "=v"(r) : "v"(a), "v"(b));
    return r;
}
__device__ __forceinline__ float vmax(float a, float b) {
    float r;
    asm("v_max_f32 %0, %1, %2" : "=v"(r) : "v"(a), "v"(b));
    return r;
}

// sorted top-5 insert: min(Kb,max(Ka,v)) == med3(Ka,Kb,v) for Ka<=Kb
#define INS5(K0, K1, K2, K3, K4, V)                                       \
    do {                                                                  \
        float _v = (V);                                                   \
        K4 = __builtin_amdgcn_fmed3f(K3, K4, _v);                         \
        K3 = __builtin_amdgcn_fmed3f(K2, K3, _v);                         \
        K2 = __builtin_amdgcn_fmed3f(K1, K2, _v);                         \
        K1 = __builtin_amdgcn_fmed3f(K0, K1, _v);                         \
        K0 = vmin(K0, _v);                                                \
    } while (0)

// lowest-5 of two sorted-5 lists (result in a0..a4)
#define MERGE55(a0, a1, a2, a3, a4, b0, b1, b2, b3, b4)                   \
    do {                                                                  \
        float r0 = vmin(a0, b0);                                          \
        float r1 = vmin(vmin(a1, b1), vmax(a0, b0));                      \
        float r2 = vmin(vmin(a2, b2), vmin(vmax(a0, b1), vmax(a1, b0)));  \
        float r3 = vmin(vmin(a3, b3),                                     \
                        vmin(vmax(a0, b2), vmin(vmax(a1, b1), vmax(a2, b0)))); \
        float r4 = vmin(vmin(a4, b4),                                     \
                        vmin(vmin(vmax(a0, b3), vmax(a1, b2)),            \
                             vmin(vmax(a2, b1), vmax(a3, b0))));          \
        a0 = r0; a1 = r1; a2 = r2; a3 = r3; a4 = r4;                      \
    } while (0)

// ---------------- tiny kernels (fallback path) ----------------
__global__ void finalize_kernel(const float* acc, float* out) {
    out[0] = acc[0] / (acc[1] * (float)KNN);
}
__global__ void init_acc_kernel(float* acc) { acc[0] = 0.0f; acc[1] = 0.0f; }

// ================= grid pipeline =================

__device__ __forceinline__ int cell_of(float x, float y, float z) {
    int cx = (int)floorf((x + GRANGE) * INVH);
    int cy = (int)floorf((y + GRANGE) * INVH);
    int cz = (int)floorf((z + GRANGE) * INVH);
    cx = min(max(cx, 0), G - 1);
    cy = min(max(cy, 0), G - 1);
    cz = min(max(cz, 0), G - 1);
    return (cz * G + cy) * G + cx;
}

__global__ void bin_count_kernel(const float* __restrict__ src,
                                 const float* __restrict__ tgt,
                                 int ms, int nt,
                                 int* __restrict__ cnt_s,
                                 int* __restrict__ cnt_t) {
    int i = blockIdx.x * blockDim.x + threadIdx.x;
    int n = ms + nt;
    for (; i < n; i += gridDim.x * blockDim.x) {
        bool isT = (i >= ms);
        const float* p = isT ? (tgt + 3 * (size_t)(i - ms)) : (src + 3 * (size_t)i);
        float x = p[0], y = p[1], z = p[2];
        if (isT && x == 0.0f && y == 0.0f && z == 0.0f) continue;
        atomicAdd((isT ? cnt_t : cnt_s) + cell_of(x, y, z), 1);
    }
}

// exclusive scan of NCPAD padded counts; block 0 -> targets, 1 -> sources.
__global__ __launch_bounds__(1024) void scan_kernel(int* ct, int* ot, int* cs, int* os) {
    __shared__ int psum[1024];
    int* c = blockIdx.x ? cs : ct;
    int* o = blockIdx.x ? os : ot;
    const int t = threadIdx.x;
    int4 v[6];
    const int4* c4 = reinterpret_cast<const int4*>(c) + t * 6;
#pragma unroll
    for (int j = 0; j < 6; ++j) v[j] = c4[j];
    int s = 0;
#pragma unroll
    for (int j = 0; j < 6; ++j) s += v[j].x + v[j].y + v[j].z + v[j].w;
    psum[t] = s;
    __syncthreads();
    for (int d = 1; d < 1024; d <<= 1) {
        int x = (t >= d) ? psum[t - d] : 0;
        __syncthreads();
        psum[t] += x;
        __syncthreads();
    }
    int run = t ? psum[t - 1] : 0;
    int4* o4 = reinterpret_cast<int4*>(o) + t * 6;
    int4* cc4 = reinterpret_cast<int4*>(c) + t * 6;
#pragma unroll
    for (int j = 0; j < 6; ++j) {
        int4 w;
        w.x = run; run += v[j].x;
        w.y = run; run += v[j].y;
        w.z = run; run += v[j].z;
        w.w = run; run += v[j].w;
        o4[j] = w;
        cc4[j] = w;  // cursor for scatter
    }
    if (t == 1023) o[NCPAD] = run;
}

__global__ void scatter_kernel(const float* __restrict__ src,
                               const float* __restrict__ tgt,
                               int ms, int nt,
                               int* __restrict__ cur_s, int* __restrict__ cur_t,
                               float4* __restrict__ pts_s,
                               float4* __restrict__ pts_t) {
    int i = blockIdx.x * blockDim.x + threadIdx.x;
    int n = ms + nt;
    for (; i < n; i += gridDim.x * blockDim.x) {
        bool isT = (i >= ms);
        const float* p = isT ? (tgt + 3 * (size_t)(i - ms)) : (src + 3 * (size_t)i);
        float x = p[0], y = p[1], z = p[2];
        if (isT && x == 0.0f && y == 0.0f && z == 0.0f) continue;
        int cell = cell_of(x, y, z);
        int slot = atomicAdd((isT ? cur_t : cur_s) + cell, 1);
        float w = fmaf(x, x, fmaf(y, y, z * z));
        (isT ? pts_t : pts_s)[slot] = make_float4(x, y, z, w);
    }
}

// ---- query: chunks of 16 consecutive sources, 16 lanes each. Ring<=1,
// prefetched row ranges, rows pruned by a CHEAP valid bound (group-min of
// per-chain k4). Exact final merge decides done vs tail. ----
__global__ __launch_bounds__(BLOCK) void knn_query_kernel(
        const float4* __restrict__ pts_s, const float4* __restrict__ pts_t,
        const int* __restrict__ off_t, float* __restrict__ acc,
        int* __restrict__ tail, int* __restrict__ tailcnt, int ms, int nchunk) {
    __shared__ float redS[4], redC[4];

    const int tid = threadIdx.x;
    const int g = tid >> 4;
    const int m = tid & 15;
    float tsum = 0.0f, tcnt = 0.0f;

    for (int c = blockIdx.x; c < nchunk; c += gridDim.x) {
        const int sidx = c * SPC + g;
        const bool live = (sidx < ms);

        float4 sp = pts_s[live ? sidx : 0];
        const float s2 = sp.w;
        const float nx = -2.0f * sp.x, ny = -2.0f * sp.y, nz = -2.0f * sp.z;

        int cx = (int)floorf((sp.x + GRANGE) * INVH);
        int cy = (int)floorf((sp.y + GRANGE) * INVH);
        int cz = (int)floorf((sp.z + GRANGE) * INVH);
        cx = min(max(cx, 0), G - 1);
        cy = min(max(cy, 0), G - 1);
        cz = min(max(cz, 0), G - 1);
        const int xlo = max(cx - 1, 0), xhi = min(cx + 1, G - 1);
        const float y0 = -GRANGE + cy * H, y1 = y0 + H;
        const float z0 = -GRANGE + cz * H, z1 = z0 + H;

        // ---- prefetch all 9 row ranges (independent loads, one batch) ----
        const int DY[9] = {0, -1, 1, 0, 0, -1, -1, 1, 1};
        const int DZ[9] = {0, 0, 0, -1, 1, -1, 1, -1, 1};
        int rst[9], ren[9];
        float rb[9];
#pragma unroll
        for (int r = 0; r < 9; ++r) {
            const int yy = cy + DY[r], zz = cz + DZ[r];
            const bool ok = ((unsigned)yy < G) && ((unsigned)zz < G);
            const int base = (zz * G + yy) * G;
            rst[r] = ok ? off_t[base + xlo] : 0;
            ren[r] = ok ? off_t[base + xhi + 1] : 0;
            float dys = (DY[r] < 0) ? (sp.y - y0) : ((DY[r] > 0) ? (y1 - sp.y) : 0.0f);
            float dzs = (DZ[r] < 0) ? (sp.z - z0) : ((DZ[r] > 0) ? (z1 - sp.z) : 0.0f);
            dys = fmaxf(dys, 0.0f);  // clamped sources sit outside their cell
            dzs = fmaxf(dzs, 0.0f);
            rb[r] = fmaf(dys, dys, dzs * dzs);
        }

        // two interleaved top-5 chains (q = d^2 - s2)
        float a0 = 1e20f, a1 = 1e20f, a2 = 1e20f, a3 = 1e20f, a4 = 1e20f;
        float b0 = 1e20f, b1 = 1e20f, b2 = 1e20f, b3 = 1e20f, b4 = 1e20f;

        auto scan_range = [&](int st, int en) {
            for (int i = st + m; i < en; i += 2 * LPS) {
                float4 t1 = pts_t[i];
                int i2 = i + LPS;
                bool h2 = (i2 < en);
                float4 t2 = pts_t[h2 ? i2 : i];
                float qa = fmaf(nx, t1.x, fmaf(ny, t1.y, fmaf(nz, t1.z, t1.w)));
                float qb = h2 ? fmaf(nx, t2.x, fmaf(ny, t2.y, fmaf(nz, t2.z, t2.w)))
                              : 1e20f;
                INS5(a0, a1, a2, a3, a4, qa);
                INS5(b0, b1, b2, b3, b4, qb);
            }
        };

        // own row first (unpruned)
        scan_range(rst[0], ren[0]);

        // CHEAP valid bound: any chain's k4 bounds the union 5th-smallest
        // from above (its own 5 entries are <= it). Group-min via butterfly.
        float bq = vmin(a4, b4);
#pragma unroll
        for (int o = 8; o >= 1; o >>= 1) bq = vmin(bq, __shfl_xor(bq, o));
        const float lim = bq + s2;

        // remaining 8 rows, slab-pruned (conservative-exact)
#pragma unroll
        for (int r = 1; r < 9; ++r) {
            if (lim > rb[r]) scan_range(rst[r], ren[r]);
        }

        // exact final merge (destructive; all lanes end with the result)
        MERGE55(a0, a1, a2, a3, a4, b0, b1, b2, b3, b4);
#pragma unroll
        for (int o = 8; o >= 1; o >>= 1) {
            float c0 = __shfl_xor(a0, o);
            float c1 = __shfl_xor(a1, o);
            float c2 = __shfl_xor(a2, o);
            float c3 = __shfl_xor(a3, o);
            float c4 = __shfl_xor(a4, o);
            MERGE55(a0, a1, a2, a3, a4, c0, c1, c2, c3, c4);
        }

        if (live && m == 0) {
            const bool valid = (sp.x != 0.0f) || (sp.y != 0.0f) || (sp.z != 0.0f);
            if (valid) {
                const bool inbox = fabsf(sp.x) <= GRANGE &&
                                   fabsf(sp.y) <= GRANGE && fabsf(sp.z) <= GRANGE;
                if (inbox && (a4 + s2 <= H * H)) {  // exact: rest >= H away
                    tsum += sqrtf(fmaxf(a0 + s2, 1e-12f)) +
                            sqrtf(fmaxf(a1 + s2, 1e-12f)) +
                            sqrtf(fmaxf(a2 + s2, 1e-12f)) +
                            sqrtf(fmaxf(a3 + s2, 1e-12f)) +
                            sqrtf(fmaxf(a4 + s2, 1e-12f));
                    tcnt += 1.0f;
                } else {
                    int ti = atomicAdd(tailcnt, 1);
                    tail[ti] = sidx;
                }
            }
        }
    }

    // block reduce -> 2 atomics
#pragma unroll
    for (int off = 32; off >= 1; off >>= 1) {
        tsum += __shfl_down(tsum, off);
        tcnt += __shfl_down(tcnt, off);
    }
    const int wv = tid >> 6;
    if ((tid & 63) == 0) { redS[wv] = tsum; redC[wv] = tcnt; }
    __syncthreads();
    if (tid == 0) {
        float s = redS[0] + redS[1] + redS[2] + redS[3];
        float c = redC[0] + redC[1] + redC[2] + redC[3];
        if (s != 0.0f || c != 0.0f) {
            atomicAdd(&acc[0], s);
            atomicAdd(&acc[1], c);
        }
    }
}

// ---- tail walker: one WAVE per tail source; within a shell the rows are
// distributed ACROSS LANES (parallel range loads + private scans), cheap
// wave-min(k4) stop bound per shell, one exact merge at the end. ----
__global__ __launch_bounds__(BLOCK) void knnT_kernel(
        const float4* __restrict__ pts_s, const float4* __restrict__ pts_t,
        const int* __restrict__ off_t, const int* __restrict__ tail,
        const int* __restrict__ tailcnt, float* __restrict__ acc,
        int* __restrict__ ticket, float* __restrict__ out) {
    __shared__ float redS[4], redC[4];
    const int T = *tailcnt;
    const int tid = threadIdx.x;
    const int lane = tid & 63, wv = tid >> 6;
    const int wid = blockIdx.x * WAVES_PER_BLOCK + wv;
    const int nwaves = gridDim.x * WAVES_PER_BLOCK;

    float wsum = 0.0f, wcnt = 0.0f;  // meaningful on lane 0

    for (int w = wid; w < T; w += nwaves) {
        const int sidx = tail[w];
        float4 sp = pts_s[sidx];  // wave-uniform
        const float s2 = sp.w;
        const float nx = -2.0f * sp.x, ny = -2.0f * sp.y, nz = -2.0f * sp.z;

        int cx = (int)floorf((sp.x + GRANGE) * INVH);
        int cy = (int)floorf((sp.y + GRANGE) * INVH);
        int cz = (int)floorf((sp.z + GRANGE) * INVH);
        cx = min(max(cx, 0), G - 1);
        cy = min(max(cy, 0), G - 1);
        cz = min(max(cz, 0), G - 1);
        const bool inbox = fabsf(sp.x) <= GRANGE && fabsf(sp.y) <= GRANGE &&
                           fabsf(sp.z) <= GRANGE;
        const int covermax = max(max(max(cx, G - 1 - cx), max(cy, G - 1 - cy)),
                                 max(cz, G - 1 - cz));

        float a0 = 1e20f, a1 = 1e20f, a2 = 1e20f, a3 = 1e20f, a4 = 1e20f;

        auto scan_cells = [&](int base, int xa, int xb) {  // per-lane serial
            const int st = off_t[base + xa];
            const int en = off_t[base + xb + 1];
            for (int i = st; i < en; ++i) {
                float4 t = pts_t[i];
                float q = fmaf(nx, t.x, fmaf(ny, t.y, fmaf(nz, t.z, t.w)));
                INS5(a0, a1, a2, a3, a4, q);
            }
        };

        for (int r = 0; ; ++r) {
            const int wdt = 2 * r + 1;
            const int nrows = wdt * wdt;
            // lanes take rows k = lane, lane+64, ... of the (dy,dz) square
            for (int k = lane; k < nrows; k += 64) {
                const int dz = k / wdt - r;
                const int dy = k - (dz + r) * wdt - r;
                const int yy = cy + dy, zz = cz + dz;
                if ((unsigned)yy >= G || (unsigned)zz >= G) continue;
                const int base = (zz * G + yy) * G;
                const bool perim = (dy == -r || dy == r || dz == -r || dz == r);
                if (perim) {
                    const int xa = max(cx - r, 0), xb = min(cx + r, G - 1);
                    if (xa <= xb) scan_cells(base, xa, xb);
                } else {
                    const int xl = cx - r;
                    if (xl >= 0) scan_cells(base, xl, xl);
                    const int xr = cx + r;
                    if (xr < G) scan_cells(base, xr, xr);
                }
            }
            // cheap valid stop bound: wave-min of per-lane k4
            float bq = a4;
#pragma unroll
            for (int o = 32; o >= 1; o >>= 1) bq = vmin(bq, __shfl_xor(bq, o));
            const float rh = (float)r * H;
            if ((inbox && (bq + s2 <= rh * rh)) || r >= covermax) break;
        }

        // exact final merge across the wave
#pragma unroll
        for (int o = 32; o >= 1; o >>= 1) {
            float c0 = __shfl_xor(a0, o);
            float c1 = __shfl_xor(a1, o);
            float c2 = __shfl_xor(a2, o);
            float c3 = __shfl_xor(a3, o);
            float c4 = __shfl_xor(a4, o);
            MERGE55(a0, a1, a2, a3, a4, c0, c1, c2, c3, c4);
        }

        if (lane == 0) {
            wsum += sqrtf(fmaxf(a0 + s2, 1e-12f)) + sqrtf(fmaxf(a1 + s2, 1e-12f)) +
                    sqrtf(fmaxf(a2 + s2, 1e-12f)) + sqrtf(fmaxf(a3 + s2, 1e-12f)) +
                    sqrtf(fmaxf(a4 + s2, 1e-12f));
            wcnt += 1.0f;
        }
    }

    if (lane == 0) { redS[wv] = wsum; redC[wv] = wcnt; }
    __syncthreads();
    if (tid == 0) {
        float s = redS[0] + redS[1] + redS[2] + redS[3];
        float c = redC[0] + redC[1] + redC[2] + redC[3];
        if (s != 0.0f || c != 0.0f) {
            atomicAdd(&acc[0], s);
            atomicAdd(&acc[1], c);
        }
        __threadfence();
        int t = atomicAdd(ticket, 1);
        if (t == (int)gridDim.x - 1) {
            float ss = atomicAdd(&acc[0], 0.0f);  // coherent read
            float cc = atomicAdd(&acc[1], 0.0f);
            out[0] = ss / (cc * (float)KNN);
        }
    }
}

// ================= fallback: round-4 split path =================

__global__ __launch_bounds__(BLOCK, 4) void knn_split_kernel(
        const float* __restrict__ src, const float* __restrict__ tgt,
        float* __restrict__ partials, int ms, int nt, int nth, int spad) {
    __shared__ __align__(16) float xs[TILE_T];
    __shared__ __align__(16) float ys[TILE_T];
    __shared__ __align__(16) float zs[TILE_T];
    __shared__ __align__(16) float w2[TILE_T];

    const int tid = threadIdx.x;
    const int wv = tid >> 6;
    const int lane = tid & 63;
    const int sbase = (blockIdx.x * WAVES_PER_BLOCK + wv) * SRCW;
    const int half = blockIdx.y;
    const int hbase = half * nth;
    const int hend = min(nt, hbase + nth);

    float nx[SRCW], ny[SRCW], nz[SRCW];
#pragma unroll
    for (int s = 0; s < SRCW; ++s) {
        int sp = sbase + s;
        float x = 0.0f, y = 0.0f, z = 0.0f;
        if (sp < ms) {
            x = src[3 * sp + 0];
            y = src[3 * sp + 1];
            z = src[3 * sp + 2];
        }
        nx[s] = -2.0f * x; ny[s] = -2.0f * y; nz[s] = -2.0f * z;
    }
    float q0[SRCW], q1[SRCW], q2[SRCW], q3[SRCW], q4[SRCW];
#pragma unroll
    for (int s = 0; s < SRCW; ++s) {
        q0[s] = 1e30f; q1[s] = 1e30f; q2[s] = 1e30f; q3[s] = 1e30f; q4[s] = 1e30f;
    }

    for (int t0 = hbase; t0 < hend; t0 += TILE_T) {
        int cnt = min(TILE_T, hend - t0);
        for (int t = tid; t < TILE_T; t += BLOCK) {
            float x = 1e10f, y = 0.0f, z = 0.0f;
            if (t < cnt) {
                x = tgt[3 * (size_t)(t0 + t) + 0];
                y = tgt[3 * (size_t)(t0 + t) + 1];
                z = tgt[3 * (size_t)(t0 + t) + 2];
                if (x == 0.0f && y == 0.0f && z == 0.0f) { x = 1e10f; y = 0.0f; z = 0.0f; }
            }
            xs[t] = x; ys[t] = y; zs[t] = z;
            w2[t] = fmaf(x, x, fmaf(y, y, z * z));
        }
        __syncthreads();
#pragma unroll 2
        for (int i = 0; i < TILE_T / 256; ++i) {
            int t = (i << 8) + (lane << 2);
            float4 x4 = *reinterpret_cast<const float4*>(&xs[t]);
            float4 y4 = *reinterpret_cast<const float4*>(&ys[t]);
            float4 z4 = *reinterpret_cast<const float4*>(&zs[t]);
            float4 w4 = *reinterpret_cast<const float4*>(&w2[t]);
#pragma unroll
            for (int s = 0; s < SRCW; ++s) {
                float qa = fmaf(nx[s], x4.x, fmaf(ny[s], y4.x, fmaf(nz[s], z4.x, w4.x)));
                float qb = fmaf(nx[s], x4.y, fmaf(ny[s], y4.y, fmaf(nz[s], z4.y, w4.y)));
                float qc = fmaf(nx[s], x4.z, fmaf(ny[s], y4.z, fmaf(nz[s], z4.z, w4.z)));
                float qd = fmaf(nx[s], x4.w, fmaf(ny[s], y4.w, fmaf(nz[s], z4.w, w4.w)));
                INS5(q0[s], q1[s], q2[s], q3[s], q4[s], qa);
                INS5(q0[s], q1[s], q2[s], q3[s], q4[s], qb);
                INS5(q0[s], q1[s], q2[s], q3[s], q4[s], qc);
                INS5(q0[s], q1[s], q2[s], q3[s], q4[s], qd);
            }
        }
        __syncthreads();
    }
#pragma unroll
    for (int off = 32; off >= 1; off >>= 1) {
#pragma unroll
        for (int s = 0; s < SRCW; ++s) {
            float b0 = __shfl_xor(q0[s], off);
            float b1 = __shfl_xor(q1[s], off);
            float b2 = __shfl_xor(q2[s], off);
            float b3 = __shfl_xor(q3[s], off);
            float b4 = __shfl_xor(q4[s], off);
            MERGE55(q0[s], q1[s], q2[s], q3[s], q4[s], b0, b1, b2, b3, b4);
        }
    }
    if (lane == 0) {
        float* base = partials + ((size_t)half * spad + sbase) * 8;
#pragma unroll
        for (int s = 0; s < SRCW; ++s) {
            if (sbase + s < ms) {
                *reinterpret_cast<float4*>(base + 8 * s) =
                    make_float4(q0[s], q1[s], q2[s], q3[s]);
                *reinterpret_cast<float4*>(base + 8 * s + 4) =
                    make_float4(q4[s], 0.0f, 0.0f, 0.0f);
            }
        }
    }
}

__global__ __launch_bounds__(BLOCK) void merge_kernel(
        const float* __restrict__ src, const float* __restrict__ partials,
        float* __restrict__ acc, int ms, int spad) {
    __shared__ float red_s[WAVES_PER_BLOCK];
    __shared__ float red_c[WAVES_PER_BLOCK];
    const int tid = threadIdx.x;
    const int sp = blockIdx.x * BLOCK + tid;
    float ssum = 0.0f, scnt = 0.0f;
    if (sp < ms) {
        const float* r0p = partials + (size_t)sp * 8;
        const float* r1p = partials + ((size_t)spad + sp) * 8;
        float4 lo0 = *reinterpret_cast<const float4*>(r0p);
        float a4 = r0p[4];
        float4 lo1 = *reinterpret_cast<const float4*>(r1p);
        float b4 = r1p[4];
        float a0 = lo0.x, a1 = lo0.y, a2 = lo0.z, a3 = lo0.w;
        MERGE55(a0, a1, a2, a3, a4, lo1.x, lo1.y, lo1.z, lo1.w, b4);
        float x = src[3 * sp + 0];
        float y = src[3 * sp + 1];
        float z = src[3 * sp + 2];
        bool valid = (x != 0.0f) || (y != 0.0f) || (z != 0.0f);
        float s2 = fmaf(x, x, fmaf(y, y, z * z));
        if (valid) {
            ssum = sqrtf(fmaxf(a0 + s2, 1e-12f)) + sqrtf(fmaxf(a1 + s2, 1e-12f)) +
                   sqrtf(fmaxf(a2 + s2, 1e-12f)) + sqrtf(fmaxf(a3 + s2, 1e-12f)) +
                   sqrtf(fmaxf(a4 + s2, 1e-12f));
            scnt = 1.0f;
        }
    }
#pragma unroll
    for (int off = 32; off >= 1; off >>= 1) {
        ssum += __shfl_down(ssum, off);
        scnt += __shfl_down(scnt, off);
    }
    if ((tid & 63) == 0) { red_s[tid >> 6] = ssum; red_c[tid >> 6] = scnt; }
    __syncthreads();
    if (tid == 0) {
        float s = 0.0f, c = 0.0f;
#pragma unroll
        for (int i = 0; i < WAVES_PER_BLOCK; ++i) { s += red_s[i]; c += red_c[i]; }
        atomicAdd(&acc[0], s);
        atomicAdd(&acc[1], c);
    }
}

// ---------------- launch ----------------

extern "C" void kernel_launch(void* const* d_in, const int* in_sizes, int n_in,
                              void* d_out, int out_size, void* d_ws, size_t ws_size,
                              hipStream_t stream) {
    const float* src = (const float*)d_in[0];
    const float* tgt = (const float*)d_in[1];
    const int ms = in_sizes[0] / 3;
    const int nt = in_sizes[1] / 3;

    // workspace layout (zeroed header first: acc, ticket, tailcnt, cnt_t/s)
    char* p = (char*)d_ws;
    auto take = [&p](size_t bytes) {
        char* r = p;
        p += (bytes + 15) & ~(size_t)15;
        return r;
    };
    float* acc    = (float*)take(16);            // acc[0], acc[1], ticket, tailcnt
    int* ticket   = (int*)(acc + 2);
    int* tailcnt  = (int*)(acc + 3);
    int* cnt_t    = (int*)take(NCPAD * sizeof(int));
    int* cnt_s    = (int*)take(NCPAD * sizeof(int));
    const size_t zero_bytes = (size_t)((char*)(cnt_s + NCPAD) - (char*)d_ws);
    int* off_t    = (int*)take((NCPAD + 1) * sizeof(int));
    int* off_s    = (int*)take((NCPAD + 1) * sizeof(int));
    float4* pts_t = (float4*)take((size_t)nt * sizeof(float4));
    float4* pts_s = (float4*)take((size_t)ms * sizeof(float4));
    int* tail     = (int*)take((size_t)ms * sizeof(int));
    const size_t need_grid = (size_t)(p - (char*)d_ws);

    if (ws_size >= need_grid) {
        const int n = ms + nt;
        hipMemsetAsync(d_ws, 0, zero_bytes, stream);
        bin_count_kernel<<<(n + 255) / 256, 256, 0, stream>>>(src, tgt, ms, nt,
                                                              cnt_s, cnt_t);
        scan_kernel<<<2, 1024, 0, stream>>>(cnt_t, off_t, cnt_s, off_s);
        scatter_kernel<<<(n + 255) / 256, 256, 0, stream>>>(src, tgt, ms, nt,
                                                            cnt_s, cnt_t, pts_s, pts_t);
        const int nchunk = (ms + SPC - 1) / SPC;
        knn_query_kernel<<<QBLOCKS, BLOCK, 0, stream>>>(pts_s, pts_t, off_t, acc,
                                                        tail, tailcnt, ms, nchunk);
        knnT_kernel<<<TBLOCKS, BLOCK, 0, stream>>>(pts_s, pts_t, off_t, tail,
                                                   tailcnt, acc, ticket,
                                                   (float*)d_out);
        return;
    }

    // fallback: round-4 split path
    float* acc2 = (float*)d_ws;
    init_acc_kernel<<<1, 1, 0, stream>>>(acc2);
    const int ngroups = (ms + SRC_PER_BLOCK - 1) / SRC_PER_BLOCK;
    const int spad = ngroups * SRC_PER_BLOCK;
    int nth = (nt + NSPLIT - 1) / NSPLIT;
    nth = (nth + TILE_T - 1) / TILE_T * TILE_T;
    float* partials = (float*)((char*)d_ws + 16);
    dim3 grid(ngroups, NSPLIT);
    knn_split_kernel<<<grid, BLOCK, 0, stream>>>(src, tgt, partials, ms, nt, nth, spad);
    merge_kernel<<<(ms + BLOCK - 1) / BLOCK, BLOCK, 0, stream>>>(src, partials,
                                                                 acc2, ms, spad);
    finalize_kernel<<<1, 1, 0, stream>>>(acc2, (float*)d_out);
}

// Round 12
// 96.609 us; speedup vs baseline: 1.5307x; 1.2009x over previous
//
#include <hip/hip_runtime.h>
#include <math.h>

#define KNN 5
#define BLOCK 256

// ---- cell grid ----
#define G 28
#define NC (G * G * G)        // 21952
#define NCPAD 24576           // padded for scan kernel (1024*24)
#define GRANGE 6.0f
#define H (2.0f * GRANGE / (float)G)
#define INVH ((float)G / (2.0f * GRANGE))
#define LPS 16                // lanes per source (query kernel)
#define SPC (BLOCK / LPS)     // sources per chunk (16)
#define QBLOCKS 1024          // query grid (1 chunk per block)
#define TBLOCKS 256           // tail-walker grid (256*4 = 1024 waves)

// ---- fallback (round-4 split path) params ----
#define TILE_T 2048
#define WAVES_PER_BLOCK (BLOCK / 64)
#define SRCW 8
#define SRC_PER_BLOCK (WAVES_PER_BLOCK * SRCW)
#define NSPLIT 2

__device__ __forceinline__ float vmin(float a, float b) {
    float r;
    asm("v_min_f32 %0, %1, %2" : "=v"(r) : "v"(a), "v"(b));
    return r;
}
__device__ __forceinline__ float vmax(float a, float b) {
    float r;
    asm("v_max_f32 %0, %1, %2" : "=v"(r) : "v"(a), "v"(b));
    return r;
}

// sorted top-5 insert: min(Kb,max(Ka,v)) == med3(Ka,Kb,v) for Ka<=Kb
#define INS5(K0, K1, K2, K3, K4, V)                                       \
    do {                                                                  \
        float _v = (V);                                                   \
        K4 = __builtin_amdgcn_fmed3f(K3, K4, _v);                         \
        K3 = __builtin_amdgcn_fmed3f(K2, K3, _v);                         \
        K2 = __builtin_amdgcn_fmed3f(K1, K2, _v);                         \
        K1 = __builtin_amdgcn_fmed3f(K0, K1, _v);                         \
        K0 = vmin(K0, _v);                                                \
    } while (0)

// lowest-5 of two sorted-5 lists (result in a0..a4)
#define MERGE55(a0, a1, a2, a3, a4, b0, b1, b2, b3, b4)                   \
    do {                                                                  \
        float r0 = vmin(a0, b0);                                          \
        float r1 = vmin(vmin(a1, b1), vmax(a0, b0));                      \
        float r2 = vmin(vmin(a2, b2), vmin(vmax(a0, b1), vmax(a1, b0)));  \
        float r3 = vmin(vmin(a3, b3),                                     \
                        vmin(vmax(a0, b2), vmin(vmax(a1, b1), vmax(a2, b0)))); \
        float r4 = vmin(vmin(a4, b4),                                     \
                        vmin(vmin(vmax(a0, b3), vmax(a1, b2)),            \
                             vmin(vmax(a2, b1), vmax(a3, b0))));          \
        a0 = r0; a1 = r1; a2 = r2; a3 = r3; a4 = r4;                      \
    } while (0)

// ---------------- tiny kernels (fallback path) ----------------
__global__ void finalize_kernel(const float* acc, float* out) {
    out[0] = acc[0] / (acc[1] * (float)KNN);
}
__global__ void init_acc_kernel(float* acc) { acc[0] = 0.0f; acc[1] = 0.0f; }

// ================= grid pipeline =================

__device__ __forceinline__ int cell_of(float x, float y, float z) {
    int cx = (int)floorf((x + GRANGE) * INVH);
    int cy = (int)floorf((y + GRANGE) * INVH);
    int cz = (int)floorf((z + GRANGE) * INVH);
    cx = min(max(cx, 0), G - 1);
    cy = min(max(cy, 0), G - 1);
    cz = min(max(cz, 0), G - 1);
    return (cz * G + cy) * G + cx;
}

__global__ void bin_count_kernel(const float* __restrict__ src,
                                 const float* __restrict__ tgt,
                                 int ms, int nt,
                                 int* __restrict__ cnt_s,
                                 int* __restrict__ cnt_t) {
    int i = blockIdx.x * blockDim.x + threadIdx.x;
    int n = ms + nt;
    for (; i < n; i += gridDim.x * blockDim.x) {
        bool isT = (i >= ms);
        const float* p = isT ? (tgt + 3 * (size_t)(i - ms)) : (src + 3 * (size_t)i);
        float x = p[0], y = p[1], z = p[2];
        if (isT && x == 0.0f && y == 0.0f && z == 0.0f) continue;
        atomicAdd((isT ? cnt_t : cnt_s) + cell_of(x, y, z), 1);
    }
}

// exclusive scan of NCPAD padded counts; block 0 -> targets, 1 -> sources.
__global__ __launch_bounds__(1024) void scan_kernel(int* ct, int* ot, int* cs, int* os) {
    __shared__ int psum[1024];
    int* c = blockIdx.x ? cs : ct;
    int* o = blockIdx.x ? os : ot;
    const int t = threadIdx.x;
    int4 v[6];
    const int4* c4 = reinterpret_cast<const int4*>(c) + t * 6;
#pragma unroll
    for (int j = 0; j < 6; ++j) v[j] = c4[j];
    int s = 0;
#pragma unroll
    for (int j = 0; j < 6; ++j) s += v[j].x + v[j].y + v[j].z + v[j].w;
    psum[t] = s;
    __syncthreads();
    for (int d = 1; d < 1024; d <<= 1) {
        int x = (t >= d) ? psum[t - d] : 0;
        __syncthreads();
        psum[t] += x;
        __syncthreads();
    }
    int run = t ? psum[t - 1] : 0;
    int4* o4 = reinterpret_cast<int4*>(o) + t * 6;
    int4* cc4 = reinterpret_cast<int4*>(c) + t * 6;
#pragma unroll
    for (int j = 0; j < 6; ++j) {
        int4 w;
        w.x = run; run += v[j].x;
        w.y = run; run += v[j].y;
        w.z = run; run += v[j].z;
        w.w = run; run += v[j].w;
        o4[j] = w;
        cc4[j] = w;  // cursor for scatter
    }
    if (t == 1023) o[NCPAD] = run;
}

__global__ void scatter_kernel(const float* __restrict__ src,
                               const float* __restrict__ tgt,
                               int ms, int nt,
                               int* __restrict__ cur_s, int* __restrict__ cur_t,
                               float4* __restrict__ pts_s,
                               float4* __restrict__ pts_t) {
    int i = blockIdx.x * blockDim.x + threadIdx.x;
    int n = ms + nt;
    for (; i < n; i += gridDim.x * blockDim.x) {
        bool isT = (i >= ms);
        const float* p = isT ? (tgt + 3 * (size_t)(i - ms)) : (src + 3 * (size_t)i);
        float x = p[0], y = p[1], z = p[2];
        if (isT && x == 0.0f && y == 0.0f && z == 0.0f) continue;
        int cell = cell_of(x, y, z);
        int slot = atomicAdd((isT ? cur_t : cur_s) + cell, 1);
        float w = fmaf(x, x, fmaf(y, y, z * z));
        (isT ? pts_t : pts_s)[slot] = make_float4(x, y, z, w);
    }
}

// ---- query: chunks of 16 consecutive sources, 16 lanes each. Ring<=1,
// prefetched row ranges, rows pruned by the EXACT merged d5 bound after the
// own-row scan. Exact final merge decides done vs tail. ----
__global__ __launch_bounds__(BLOCK) void knn_query_kernel(
        const float4* __restrict__ pts_s, const float4* __restrict__ pts_t,
        const int* __restrict__ off_t, float* __restrict__ acc,
        int* __restrict__ tail, int* __restrict__ tailcnt, int ms, int nchunk) {
    __shared__ float redS[4], redC[4];

    const int tid = threadIdx.x;
    const int g = tid >> 4;
    const int m = tid & 15;
    float tsum = 0.0f, tcnt = 0.0f;

    for (int c = blockIdx.x; c < nchunk; c += gridDim.x) {
        const int sidx = c * SPC + g;
        const bool live = (sidx < ms);

        float4 sp = pts_s[live ? sidx : 0];
        const float s2 = sp.w;
        const float nx = -2.0f * sp.x, ny = -2.0f * sp.y, nz = -2.0f * sp.z;

        int cx = (int)floorf((sp.x + GRANGE) * INVH);
        int cy = (int)floorf((sp.y + GRANGE) * INVH);
        int cz = (int)floorf((sp.z + GRANGE) * INVH);
        cx = min(max(cx, 0), G - 1);
        cy = min(max(cy, 0), G - 1);
        cz = min(max(cz, 0), G - 1);
        const int xlo = max(cx - 1, 0), xhi = min(cx + 1, G - 1);
        const float y0 = -GRANGE + cy * H, y1 = y0 + H;
        const float z0 = -GRANGE + cz * H, z1 = z0 + H;

        // ---- prefetch all 9 row ranges (independent loads, one batch) ----
        const int DY[9] = {0, -1, 1, 0, 0, -1, -1, 1, 1};
        const int DZ[9] = {0, 0, 0, -1, 1, -1, 1, -1, 1};
        int rst[9], ren[9];
        float rb[9];
#pragma unroll
        for (int r = 0; r < 9; ++r) {
            const int yy = cy + DY[r], zz = cz + DZ[r];
            const bool ok = ((unsigned)yy < G) && ((unsigned)zz < G);
            const int base = (zz * G + yy) * G;
            rst[r] = ok ? off_t[base + xlo] : 0;
            ren[r] = ok ? off_t[base + xhi + 1] : 0;
            float dys = (DY[r] < 0) ? (sp.y - y0) : ((DY[r] > 0) ? (y1 - sp.y) : 0.0f);
            float dzs = (DZ[r] < 0) ? (sp.z - z0) : ((DZ[r] > 0) ? (z1 - sp.z) : 0.0f);
            dys = fmaxf(dys, 0.0f);  // clamped sources sit outside their cell
            dzs = fmaxf(dzs, 0.0f);
            rb[r] = fmaf(dys, dys, dzs * dzs);
        }

        // two interleaved top-5 chains (q = d^2 - s2)
        float a0 = 1e20f, a1 = 1e20f, a2 = 1e20f, a3 = 1e20f, a4 = 1e20f;
        float b0 = 1e20f, b1 = 1e20f, b2 = 1e20f, b3 = 1e20f, b4 = 1e20f;

        auto scan_range = [&](int st, int en) {
            for (int i = st + m; i < en; i += 2 * LPS) {
                float4 t1 = pts_t[i];
                int i2 = i + LPS;
                bool h2 = (i2 < en);
                float4 t2 = pts_t[h2 ? i2 : i];
                float qa = fmaf(nx, t1.x, fmaf(ny, t1.y, fmaf(nz, t1.z, t1.w)));
                float qb = h2 ? fmaf(nx, t2.x, fmaf(ny, t2.y, fmaf(nz, t2.z, t2.w)))
                              : 1e20f;
                INS5(a0, a1, a2, a3, a4, qa);
                INS5(b0, b1, b2, b3, b4, qb);
            }
        };

        // own row first (unpruned)
        scan_range(rst[0], ren[0]);

        // EXACT merged d5^2 bound after own row (non-destructive)
        float lim;
        {
            float m0 = a0, m1 = a1, m2 = a2, m3 = a3, m4 = a4;
            MERGE55(m0, m1, m2, m3, m4, b0, b1, b2, b3, b4);
#pragma unroll
            for (int o = 8; o >= 1; o >>= 1) {
                float c0 = __shfl_xor(m0, o);
                float c1 = __shfl_xor(m1, o);
                float c2 = __shfl_xor(m2, o);
                float c3 = __shfl_xor(m3, o);
                float c4 = __shfl_xor(m4, o);
                MERGE55(m0, m1, m2, m3, m4, c0, c1, c2, c3, c4);
            }
            lim = m4 + s2;
        }

        // remaining 8 rows, slab-pruned (conservative-exact)
#pragma unroll
        for (int r = 1; r < 9; ++r) {
            if (lim > rb[r]) scan_range(rst[r], ren[r]);
        }

        // exact final merge (destructive; all lanes end with the result)
        MERGE55(a0, a1, a2, a3, a4, b0, b1, b2, b3, b4);
#pragma unroll
        for (int o = 8; o >= 1; o >>= 1) {
            float c0 = __shfl_xor(a0, o);
            float c1 = __shfl_xor(a1, o);
            float c2 = __shfl_xor(a2, o);
            float c3 = __shfl_xor(a3, o);
            float c4 = __shfl_xor(a4, o);
            MERGE55(a0, a1, a2, a3, a4, c0, c1, c2, c3, c4);
        }

        if (live && m == 0) {
            const bool valid = (sp.x != 0.0f) || (sp.y != 0.0f) || (sp.z != 0.0f);
            if (valid) {
                const bool inbox = fabsf(sp.x) <= GRANGE &&
                                   fabsf(sp.y) <= GRANGE && fabsf(sp.z) <= GRANGE;
                if (inbox && (a4 + s2 <= H * H)) {  // exact: rest >= H away
                    tsum += sqrtf(fmaxf(a0 + s2, 1e-12f)) +
                            sqrtf(fmaxf(a1 + s2, 1e-12f)) +
                            sqrtf(fmaxf(a2 + s2, 1e-12f)) +
                            sqrtf(fmaxf(a3 + s2, 1e-12f)) +
                            sqrtf(fmaxf(a4 + s2, 1e-12f));
                    tcnt += 1.0f;
                } else {
                    int ti = atomicAdd(tailcnt, 1);
                    tail[ti] = sidx;
                }
            }
        }
    }

    // block reduce -> 2 atomics
#pragma unroll
    for (int off = 32; off >= 1; off >>= 1) {
        tsum += __shfl_down(tsum, off);
        tcnt += __shfl_down(tcnt, off);
    }
    const int wv = tid >> 6;
    if ((tid & 63) == 0) { redS[wv] = tsum; redC[wv] = tcnt; }
    __syncthreads();
    if (tid == 0) {
        float s = redS[0] + redS[1] + redS[2] + redS[3];
        float c = redC[0] + redC[1] + redC[2] + redC[3];
        if (s != 0.0f || c != 0.0f) {
            atomicAdd(&acc[0], s);
            atomicAdd(&acc[1], c);
        }
    }
}

// ---- tail walker: one WAVE per tail source; shell rows distributed ACROSS
// LANES (parallel range loads + private scans); per-shell stop check uses
// the EXACT 64-lane merged d5 (non-destructive). ----
__global__ __launch_bounds__(BLOCK) void knnT_kernel(
        const float4* __restrict__ pts_s, const float4* __restrict__ pts_t,
        const int* __restrict__ off_t, const int* __restrict__ tail,
        const int* __restrict__ tailcnt, float* __restrict__ acc,
        int* __restrict__ ticket, float* __restrict__ out) {
    __shared__ float redS[4], redC[4];
    const int T = *tailcnt;
    const int tid = threadIdx.x;
    const int lane = tid & 63, wv = tid >> 6;
    const int wid = blockIdx.x * WAVES_PER_BLOCK + wv;
    const int nwaves = gridDim.x * WAVES_PER_BLOCK;

    float wsum = 0.0f, wcnt = 0.0f;  // meaningful on lane 0

    for (int w = wid; w < T; w += nwaves) {
        const int sidx = tail[w];
        float4 sp = pts_s[sidx];  // wave-uniform
        const float s2 = sp.w;
        const float nx = -2.0f * sp.x, ny = -2.0f * sp.y, nz = -2.0f * sp.z;

        int cx = (int)floorf((sp.x + GRANGE) * INVH);
        int cy = (int)floorf((sp.y + GRANGE) * INVH);
        int cz = (int)floorf((sp.z + GRANGE) * INVH);
        cx = min(max(cx, 0), G - 1);
        cy = min(max(cy, 0), G - 1);
        cz = min(max(cz, 0), G - 1);
        const bool inbox = fabsf(sp.x) <= GRANGE && fabsf(sp.y) <= GRANGE &&
                           fabsf(sp.z) <= GRANGE;
        const int covermax = max(max(max(cx, G - 1 - cx), max(cy, G - 1 - cy)),
                                 max(cz, G - 1 - cz));

        float a0 = 1e20f, a1 = 1e20f, a2 = 1e20f, a3 = 1e20f, a4 = 1e20f;

        auto scan_cells = [&](int base, int xa, int xb) {  // per-lane serial
            const int st = off_t[base + xa];
            const int en = off_t[base + xb + 1];
            for (int i = st; i < en; ++i) {
                float4 t = pts_t[i];
                float q = fmaf(nx, t.x, fmaf(ny, t.y, fmaf(nz, t.z, t.w)));
                INS5(a0, a1, a2, a3, a4, q);
            }
        };

        for (int r = 0; ; ++r) {
            const int wdt = 2 * r + 1;
            const int nrows = wdt * wdt;
            // lanes take rows k = lane, lane+64, ... of the (dy,dz) square
            for (int k = lane; k < nrows; k += 64) {
                const int dz = k / wdt - r;
                const int dy = k - (dz + r) * wdt - r;
                const int yy = cy + dy, zz = cz + dz;
                if ((unsigned)yy >= G || (unsigned)zz >= G) continue;
                const int base = (zz * G + yy) * G;
                const bool perim = (dy == -r || dy == r || dz == -r || dz == r);
                if (perim) {
                    const int xa = max(cx - r, 0), xb = min(cx + r, G - 1);
                    if (xa <= xb) scan_cells(base, xa, xb);
                } else {
                    const int xl = cx - r;
                    if (xl >= 0) scan_cells(base, xl, xl);
                    const int xr = cx + r;
                    if (xr < G) scan_cells(base, xr, xr);
                }
            }
            // EXACT stop bound: non-destructive 64-lane merged d5^2
            float m0 = a0, m1 = a1, m2 = a2, m3 = a3, m4 = a4;
#pragma unroll
            for (int o = 32; o >= 1; o >>= 1) {
                float c0 = __shfl_xor(m0, o);
                float c1 = __shfl_xor(m1, o);
                float c2 = __shfl_xor(m2, o);
                float c3 = __shfl_xor(m3, o);
                float c4 = __shfl_xor(m4, o);
                MERGE55(m0, m1, m2, m3, m4, c0, c1, c2, c3, c4);
            }
            const float rh = (float)r * H;
            if ((inbox && (m4 + s2 <= rh * rh)) || r >= covermax) break;
        }

        // exact final merge across the wave
#pragma unroll
        for (int o = 32; o >= 1; o >>= 1) {
            float c0 = __shfl_xor(a0, o);
            float c1 = __shfl_xor(a1, o);
            float c2 = __shfl_xor(a2, o);
            float c3 = __shfl_xor(a3, o);
            float c4 = __shfl_xor(a4, o);
            MERGE55(a0, a1, a2, a3, a4, c0, c1, c2, c3, c4);
        }

        if (lane == 0) {
            wsum += sqrtf(fmaxf(a0 + s2, 1e-12f)) + sqrtf(fmaxf(a1 + s2, 1e-12f)) +
                    sqrtf(fmaxf(a2 + s2, 1e-12f)) + sqrtf(fmaxf(a3 + s2, 1e-12f)) +
                    sqrtf(fmaxf(a4 + s2, 1e-12f));
            wcnt += 1.0f;
        }
    }

    if (lane == 0) { redS[wv] = wsum; redC[wv] = wcnt; }
    __syncthreads();
    if (tid == 0) {
        float s = redS[0] + redS[1] + redS[2] + redS[3];
        float c = redC[0] + redC[1] + redC[2] + redC[3];
        if (s != 0.0f || c != 0.0f) {
            atomicAdd(&acc[0], s);
            atomicAdd(&acc[1], c);
        }
        __threadfence();
        int t = atomicAdd(ticket, 1);
        if (t == (int)gridDim.x - 1) {
            float ss = atomicAdd(&acc[0], 0.0f);  // coherent read
            float cc = atomicAdd(&acc[1], 0.0f);
            out[0] = ss / (cc * (float)KNN);
        }
    }
}

// ================= fallback: round-4 split path =================

__global__ __launch_bounds__(BLOCK, 4) void knn_split_kernel(
        const float* __restrict__ src, const float* __restrict__ tgt,
        float* __restrict__ partials, int ms, int nt, int nth, int spad) {
    __shared__ __align__(16) float xs[TILE_T];
    __shared__ __align__(16) float ys[TILE_T];
    __shared__ __align__(16) float zs[TILE_T];
    __shared__ __align__(16) float w2[TILE_T];

    const int tid = threadIdx.x;
    const int wv = tid >> 6;
    const int lane = tid & 63;
    const int sbase = (blockIdx.x * WAVES_PER_BLOCK + wv) * SRCW;
    const int half = blockIdx.y;
    const int hbase = half * nth;
    const int hend = min(nt, hbase + nth);

    float nx[SRCW], ny[SRCW], nz[SRCW];
#pragma unroll
    for (int s = 0; s < SRCW; ++s) {
        int sp = sbase + s;
        float x = 0.0f, y = 0.0f, z = 0.0f;
        if (sp < ms) {
            x = src[3 * sp + 0];
            y = src[3 * sp + 1];
            z = src[3 * sp + 2];
        }
        nx[s] = -2.0f * x; ny[s] = -2.0f * y; nz[s] = -2.0f * z;
    }
    float q0[SRCW], q1[SRCW], q2[SRCW], q3[SRCW], q4[SRCW];
#pragma unroll
    for (int s = 0; s < SRCW; ++s) {
        q0[s] = 1e30f; q1[s] = 1e30f; q2[s] = 1e30f; q3[s] = 1e30f; q4[s] = 1e30f;
    }

    for (int t0 = hbase; t0 < hend; t0 += TILE_T) {
        int cnt = min(TILE_T, hend - t0);
        for (int t = tid; t < TILE_T; t += BLOCK) {
            float x = 1e10f, y = 0.0f, z = 0.0f;
            if (t < cnt) {
                x = tgt[3 * (size_t)(t0 + t) + 0];
                y = tgt[3 * (size_t)(t0 + t) + 1];
                z = tgt[3 * (size_t)(t0 + t) + 2];
                if (x == 0.0f && y == 0.0f && z == 0.0f) { x = 1e10f; y = 0.0f; z = 0.0f; }
            }
            xs[t] = x; ys[t] = y; zs[t] = z;
            w2[t] = fmaf(x, x, fmaf(y, y, z * z));
        }
        __syncthreads();
#pragma unroll 2
        for (int i = 0; i < TILE_T / 256; ++i) {
            int t = (i << 8) + (lane << 2);
            float4 x4 = *reinterpret_cast<const float4*>(&xs[t]);
            float4 y4 = *reinterpret_cast<const float4*>(&ys[t]);
            float4 z4 = *reinterpret_cast<const float4*>(&zs[t]);
            float4 w4 = *reinterpret_cast<const float4*>(&w2[t]);
#pragma unroll
            for (int s = 0; s < SRCW; ++s) {
                float qa = fmaf(nx[s], x4.x, fmaf(ny[s], y4.x, fmaf(nz[s], z4.x, w4.x)));
                float qb = fmaf(nx[s], x4.y, fmaf(ny[s], y4.y, fmaf(nz[s], z4.y, w4.y)));
                float qc = fmaf(nx[s], x4.z, fmaf(ny[s], y4.z, fmaf(nz[s], z4.z, w4.z)));
                float qd = fmaf(nx[s], x4.w, fmaf(ny[s], y4.w, fmaf(nz[s], z4.w, w4.w)));
                INS5(q0[s], q1[s], q2[s], q3[s], q4[s], qa);
                INS5(q0[s], q1[s], q2[s], q3[s], q4[s], qb);
                INS5(q0[s], q1[s], q2[s], q3[s], q4[s], qc);
                INS5(q0[s], q1[s], q2[s], q3[s], q4[s], qd);
            }
        }
        __syncthreads();
    }
#pragma unroll
    for (int off = 32; off >= 1; off >>= 1) {
#pragma unroll
        for (int s = 0; s < SRCW; ++s) {
            float b0 = __shfl_xor(q0[s], off);
            float b1 = __shfl_xor(q1[s], off);
            float b2 = __shfl_xor(q2[s], off);
            float b3 = __shfl_xor(q3[s], off);
            float b4 = __shfl_xor(q4[s], off);
            MERGE55(q0[s], q1[s], q2[s], q3[s], q4[s], b0, b1, b2, b3, b4);
        }
    }
    if (lane == 0) {
        float* base = partials + ((size_t)half * spad + sbase) * 8;
#pragma unroll
        for (int s = 0; s < SRCW; ++s) {
            if (sbase + s < ms) {
                *reinterpret_cast<float4*>(base + 8 * s) =
                    make_float4(q0[s], q1[s], q2[s], q3[s]);
                *reinterpret_cast<float4*>(base + 8 * s + 4) =
                    make_float4(q4[s], 0.0f, 0.0f, 0.0f);
            }
        }
    }
}

__global__ __launch_bounds__(BLOCK) void merge_kernel(
        const float* __restrict__ src, const float* __restrict__ partials,
        float* __restrict__ acc, int ms, int spad) {
    __shared__ float red_s[WAVES_PER_BLOCK];
    __shared__ float red_c[WAVES_PER_BLOCK];
    const int tid = threadIdx.x;
    const int sp = blockIdx.x * BLOCK + tid;
    float ssum = 0.0f, scnt = 0.0f;
    if (sp < ms) {
        const float* r0p = partials + (size_t)sp * 8;
        const float* r1p = partials + ((size_t)spad + sp) * 8;
        float4 lo0 = *reinterpret_cast<const float4*>(r0p);
        float a4 = r0p[4];
        float4 lo1 = *reinterpret_cast<const float4*>(r1p);
        float b4 = r1p[4];
        float a0 = lo0.x, a1 = lo0.y, a2 = lo0.z, a3 = lo0.w;
        MERGE55(a0, a1, a2, a3, a4, lo1.x, lo1.y, lo1.z, lo1.w, b4);
        float x = src[3 * sp + 0];
        float y = src[3 * sp + 1];
        float z = src[3 * sp + 2];
        bool valid = (x != 0.0f) || (y != 0.0f) || (z != 0.0f);
        float s2 = fmaf(x, x, fmaf(y, y, z * z));
        if (valid) {
            ssum = sqrtf(fmaxf(a0 + s2, 1e-12f)) + sqrtf(fmaxf(a1 + s2, 1e-12f)) +
                   sqrtf(fmaxf(a2 + s2, 1e-12f)) + sqrtf(fmaxf(a3 + s2, 1e-12f)) +
                   sqrtf(fmaxf(a4 + s2, 1e-12f));
            scnt = 1.0f;
        }
    }
#pragma unroll
    for (int off = 32; off >= 1; off >>= 1) {
        ssum += __shfl_down(ssum, off);
        scnt += __shfl_down(scnt, off);
    }
    if ((tid & 63) == 0) { red_s[tid >> 6] = ssum; red_c[tid >> 6] = scnt; }
    __syncthreads();
    if (tid == 0) {
        float s = 0.0f, c = 0.0f;
#pragma unroll
        for (int i = 0; i < WAVES_PER_BLOCK; ++i) { s += red_s[i]; c += red_c[i]; }
        atomicAdd(&acc[0], s);
        atomicAdd(&acc[1], c);
    }
}

// ---------------- launch ----------------

extern "C" void kernel_launch(void* const* d_in, const int* in_sizes, int n_in,
                              void* d_out, int out_size, void* d_ws, size_t ws_size,
                              hipStream_t stream) {
    const float* src = (const float*)d_in[0];
    const float* tgt = (const float*)d_in[1];
    const int ms = in_sizes[0] / 3;
    const int nt = in_sizes[1] / 3;

    // workspace layout (zeroed header first: acc, ticket, tailcnt, cnt_t/s)
    char* p = (char*)d_ws;
    auto take = [&p](size_t bytes) {
        char* r = p;
        p += (bytes + 15) & ~(size_t)15;
        return r;
    };
    float* acc    = (float*)take(16);            // acc[0], acc[1], ticket, tailcnt
    int* ticket   = (int*)(acc + 2);
    int* tailcnt  = (int*)(acc + 3);
    int* cnt_t    = (int*)take(NCPAD * sizeof(int));
    int* cnt_s    = (int*)take(NCPAD * sizeof(int));
    const size_t zero_bytes = (size_t)((char*)(cnt_s + NCPAD) - (char*)d_ws);
    int* off_t    = (int*)take((NCPAD + 1) * sizeof(int));
    int* off_s    = (int*)take((NCPAD + 1) * sizeof(int));
    float4* pts_t = (float4*)take((size_t)nt * sizeof(float4));
    float4* pts_s = (float4*)take((size_t)ms * sizeof(float4));
    int* tail     = (int*)take((size_t)ms * sizeof(int));
    const size_t need_grid = (size_t)(p - (char*)d_ws);

    if (ws_size >= need_grid) {
        const int n = ms + nt;
        hipMemsetAsync(d_ws, 0, zero_bytes, stream);
        bin_count_kernel<<<(n + 255) / 256, 256, 0, stream>>>(src, tgt, ms, nt,
                                                              cnt_s, cnt_t);
        scan_kernel<<<2, 1024, 0, stream>>>(cnt_t, off_t, cnt_s, off_s);
        scatter_kernel<<<(n + 255) / 256, 256, 0, stream>>>(src, tgt, ms, nt,
                                                            cnt_s, cnt_t, pts_s, pts_t);
        const int nchunk = (ms + SPC - 1) / SPC;
        knn_query_kernel<<<QBLOCKS, BLOCK, 0, stream>>>(pts_s, pts_t, off_t, acc,
                                                        tail, tailcnt, ms, nchunk);
        knnT_kernel<<<TBLOCKS, BLOCK, 0, stream>>>(pts_s, pts_t, off_t, tail,
                                                   tailcnt, acc, ticket,
                                                   (float*)d_out);
        return;
    }

    // fallback: round-4 split path
    float* acc2 = (float*)d_ws;
    init_acc_kernel<<<1, 1, 0, stream>>>(acc2);
    const int ngroups = (ms + SRC_PER_BLOCK - 1) / SRC_PER_BLOCK;
    const int spad = ngroups * SRC_PER_BLOCK;
    int nth = (nt + NSPLIT - 1) / NSPLIT;
    nth = (nth + TILE_T - 1) / TILE_T * TILE_T;
    float* partials = (float*)((char*)d_ws + 16);
    dim3 grid(ngroups, NSPLIT);
    knn_split_kernel<<<grid, BLOCK, 0, stream>>>(src, tgt, partials, ms, nt, nth, spad);
    merge_kernel<<<(ms + BLOCK - 1) / BLOCK, BLOCK, 0, stream>>>(src, partials,
                                                                 acc2, ms, spad);
    finalize_kernel<<<1, 1, 0, stream>>>(acc2, (float*)d_out);
}